// Round 1
// baseline (10215.053 us; speedup 1.0000x reference)
//
#include <hip/hip_runtime.h>
#include <math.h>

#define V_  32000
#define H_  1024
#define L_  2
#define E_  8
#define NH_ 4
#define HD_ 256
#define S_  1024
#define B_  4
#define T_  4096
#define FF_ 4096

// ---------------------------------------------------------------- embed
__global__ __launch_bounds__(256) void embed_k(const int* __restrict__ ids,
                                               const float* __restrict__ emb,
                                               float* __restrict__ x) {
    int t = blockIdx.x;
    int id = ids[t];
    const float4* src = (const float4*)(emb + (size_t)id * H_);
    float4* dst = (float4*)(x + (size_t)t * H_);
    dst[threadIdx.x] = src[threadIdx.x];
}

// ---------------------------------------------------------------- GEMM
// C[M,N] = A[M,K] @ B + bias, tiled 64x64x16, 256 thr, 4x4 microtile.
// TB=true : B is W[N,K] row-major (x @ W^T).  TB=false: B is [K,N].
// EPI: 0 none, 1 exact GELU, 2 ReLU.  M,N,K all multiples of 64/16 here.
__device__ __forceinline__ float gelu_f(float v) {
    return 0.5f * v * (1.0f + erff(v * 0.70710678118654752f));
}

template <bool TB, int EPI>
__global__ __launch_bounds__(256) void gemm_k(const float* __restrict__ A,
                                              const float* __restrict__ Bm,
                                              const float* __restrict__ bias,
                                              float* __restrict__ C,
                                              int N, int K) {
    __shared__ float As[16][68];
    __shared__ float Bs[16][68];
    const int tid = threadIdx.x;
    const int m0 = blockIdx.y * 64, n0 = blockIdx.x * 64;
    const int ty = tid >> 4, tx = tid & 15;
    const int lr = tid >> 2, lc = tid & 3;
    const float* Arow = A + (size_t)(m0 + lr) * K + lc * 4;
    float acc[4][4] = {};

    for (int k0 = 0; k0 < K; k0 += 16) {
        float4 av = *(const float4*)(Arow + k0);
        As[lc * 4 + 0][lr] = av.x; As[lc * 4 + 1][lr] = av.y;
        As[lc * 4 + 2][lr] = av.z; As[lc * 4 + 3][lr] = av.w;
        if (TB) {
            float4 wv = *(const float4*)(Bm + (size_t)(n0 + lr) * K + k0 + lc * 4);
            Bs[lc * 4 + 0][lr] = wv.x; Bs[lc * 4 + 1][lr] = wv.y;
            Bs[lc * 4 + 2][lr] = wv.z; Bs[lc * 4 + 3][lr] = wv.w;
        } else {
            int kr = tid >> 4, n4 = tid & 15;
            float4 bv = *(const float4*)(Bm + (size_t)(k0 + kr) * N + n0 + n4 * 4);
            *(float4*)&Bs[kr][n4 * 4] = bv;
        }
        __syncthreads();
#pragma unroll
        for (int k = 0; k < 16; k++) {
            float4 a4 = *(const float4*)&As[k][ty * 4];
            float4 b4 = *(const float4*)&Bs[k][tx * 4];
            const float a[4] = {a4.x, a4.y, a4.z, a4.w};
            const float b[4] = {b4.x, b4.y, b4.z, b4.w};
#pragma unroll
            for (int i = 0; i < 4; i++)
#pragma unroll
                for (int j = 0; j < 4; j++) acc[i][j] += a[i] * b[j];
        }
        __syncthreads();
    }

    float4 bb = *(const float4*)(bias + n0 + tx * 4);
    const float bbv[4] = {bb.x, bb.y, bb.z, bb.w};
#pragma unroll
    for (int i = 0; i < 4; i++) {
        float o[4];
#pragma unroll
        for (int j = 0; j < 4; j++) {
            float v = acc[i][j] + bbv[j];
            if (EPI == 1) v = gelu_f(v);
            if (EPI == 2) v = fmaxf(v, 0.0f);
            o[j] = v;
        }
        float4 ov = {o[0], o[1], o[2], o[3]};
        *(float4*)(C + (size_t)(m0 + ty * 4 + i) * N + n0 + tx * 4) = ov;
    }
}

// ------------------------------------------------- expert GEMM (gather/scatter)
// blockIdx.y = e*64 + rb.  Rows of expert e live at bucket slots off[e]..off[e]+cnt[e).
// GA: A row = list[slot]>>1 (token id), stride K.  else A row = slot.
// SC: C row = list[slot] (t*2+k), stride N.       else C row = slot.
template <int EPI, bool GA, bool SC>
__global__ __launch_bounds__(256) void gemm_exp(const float* __restrict__ A,
                                                const float* __restrict__ Bw,
                                                const float* __restrict__ bias,
                                                float* __restrict__ C,
                                                const int* __restrict__ list,
                                                const int* __restrict__ off,
                                                const int* __restrict__ cnt,
                                                int N, int K) {
    const int e = blockIdx.y >> 6;
    const int rb = blockIdx.y & 63;
    const int c = cnt[e];
    if (rb * 64 >= c) return;
    const int base = off[e];
    const float* Be = Bw + (size_t)e * K * N;
    const float* be = bias + (size_t)e * N;

    __shared__ float As[16][68];
    __shared__ float Bs[16][68];
    const int tid = threadIdx.x;
    const int n0 = blockIdx.x * 64;
    const int ty = tid >> 4, tx = tid & 15;
    const int lr = tid >> 2, lc = tid & 3;

    int rl = rb * 64 + lr;
    if (rl > c - 1) rl = c - 1;
    const int arow = GA ? (list[base + rl] >> 1) : (base + rl);
    const float* Arow = A + (size_t)arow * K + lc * 4;
    float acc[4][4] = {};

    for (int k0 = 0; k0 < K; k0 += 16) {
        float4 av = *(const float4*)(Arow + k0);
        As[lc * 4 + 0][lr] = av.x; As[lc * 4 + 1][lr] = av.y;
        As[lc * 4 + 2][lr] = av.z; As[lc * 4 + 3][lr] = av.w;
        int kr = tid >> 4, n4 = tid & 15;
        float4 bv = *(const float4*)(Be + (size_t)(k0 + kr) * N + n0 + n4 * 4);
        *(float4*)&Bs[kr][n4 * 4] = bv;
        __syncthreads();
#pragma unroll
        for (int k = 0; k < 16; k++) {
            float4 a4 = *(const float4*)&As[k][ty * 4];
            float4 b4 = *(const float4*)&Bs[k][tx * 4];
            const float a[4] = {a4.x, a4.y, a4.z, a4.w};
            const float b[4] = {b4.x, b4.y, b4.z, b4.w};
#pragma unroll
            for (int i = 0; i < 4; i++)
#pragma unroll
                for (int j = 0; j < 4; j++) acc[i][j] += a[i] * b[j];
        }
        __syncthreads();
    }

    float4 bb = *(const float4*)(be + n0 + tx * 4);
    const float bbv[4] = {bb.x, bb.y, bb.z, bb.w};
#pragma unroll
    for (int i = 0; i < 4; i++) {
        int rr = rb * 64 + ty * 4 + i;
        if (rr < c) {
            int crow = SC ? list[base + rr] : (base + rr);
            float o[4];
#pragma unroll
            for (int j = 0; j < 4; j++) {
                float v = acc[i][j] + bbv[j];
                if (EPI == 1) v = gelu_f(v);
                if (EPI == 2) v = fmaxf(v, 0.0f);
                o[j] = v;
            }
            float4 ov = {o[0], o[1], o[2], o[3]};
            *(float4*)(C + (size_t)crow * N + n0 + tx * 4) = ov;
        }
    }
}

// ---------------------------------------------------------------- attention
// Flash-style. Block = 32 queries of one (b,h). 256 thr: 32 q-groups x 8 dim-lanes.
// Each thread owns 8 float4 of the 256-dim head (d4 = dg + 8*ii).
__global__ __launch_bounds__(256) void attn_k(const float* __restrict__ qkv,
                                              float* __restrict__ ao) {
    constexpr int TK = 16;
    constexpr int ROW4 = 68;  // float4 pitch per K/V row (64 + 4 pad)
    __shared__ float4 Ks[TK * ROW4];
    __shared__ float4 Vs[TK * ROW4];

    const int bh = blockIdx.y;
    const int b = bh >> 2, h = bh & 3;
    const int q0 = blockIdx.x * 32;
    const int tid = threadIdx.x;
    const int qi = tid >> 3, dg = tid & 7;
    const int sq = q0 + qi;

    const float scale = 0.0625f;  // 1/sqrt(256)
    const float4* qrow4 = (const float4*)(qkv + (size_t)(b * S_ + sq) * 3072 + h * HD_);
    float4 qreg[8], oreg[8];
#pragma unroll
    for (int ii = 0; ii < 8; ii++) {
        float4 qv = qrow4[dg + 8 * ii];
        qreg[ii] = {qv.x * scale, qv.y * scale, qv.z * scale, qv.w * scale};
        oreg[ii] = {0.f, 0.f, 0.f, 0.f};
    }
    float m = -1e30f, l = 0.f;

    const int srow = tid >> 4;   // 0..15 staging row
    const int sc4 = tid & 15;    // 16 thr per row, 4 float4 each
    const float* kbase = qkv + (size_t)(b * S_) * 3072 + H_ + h * HD_;
    const float* vbase = kbase + H_;

    for (int kt = 0; kt < S_ / TK; kt++) {
        const int krow = kt * TK + srow;
        const float4* kg = (const float4*)(kbase + (size_t)krow * 3072);
        const float4* vg = (const float4*)(vbase + (size_t)krow * 3072);
#pragma unroll
        for (int ii = 0; ii < 4; ii++) {
            int j4 = sc4 + 16 * ii;
            Ks[srow * ROW4 + j4] = kg[j4];
            Vs[srow * ROW4 + j4] = vg[j4];
        }
        __syncthreads();

        float sc_[TK];
        float tmax = -1e30f;
#pragma unroll
        for (int j = 0; j < TK; j++) {
            float p = 0.f;
#pragma unroll
            for (int ii = 0; ii < 8; ii++) {
                float4 kv = Ks[j * ROW4 + dg + 8 * ii];
                p += qreg[ii].x * kv.x + qreg[ii].y * kv.y +
                     qreg[ii].z * kv.z + qreg[ii].w * kv.w;
            }
            p += __shfl_xor(p, 1);
            p += __shfl_xor(p, 2);
            p += __shfl_xor(p, 4);
            sc_[j] = p;
            tmax = fmaxf(tmax, p);
        }
        float mnew = fmaxf(m, tmax);
        float corr = __expf(m - mnew);
        l *= corr;
#pragma unroll
        for (int ii = 0; ii < 8; ii++) {
            oreg[ii].x *= corr; oreg[ii].y *= corr;
            oreg[ii].z *= corr; oreg[ii].w *= corr;
        }
#pragma unroll
        for (int j = 0; j < TK; j++) {
            float p = __expf(sc_[j] - mnew);
            l += p;
#pragma unroll
            for (int ii = 0; ii < 8; ii++) {
                float4 vv = Vs[j * ROW4 + dg + 8 * ii];
                oreg[ii].x += p * vv.x; oreg[ii].y += p * vv.y;
                oreg[ii].z += p * vv.z; oreg[ii].w += p * vv.w;
            }
        }
        m = mnew;
        __syncthreads();
    }

    const float inv = 1.f / l;
    float4* orow4 = (float4*)(ao + (size_t)(b * S_ + sq) * H_ + h * HD_);
#pragma unroll
    for (int ii = 0; ii < 8; ii++) {
        float4 ov = {oreg[ii].x * inv, oreg[ii].y * inv,
                     oreg[ii].z * inv, oreg[ii].w * inv};
        orow4[dg + 8 * ii] = ov;
    }
}

// ---------------------------------------------------------------- layernorm
// out[row] = LN(xin[row] + res[row]) * g + b.  One block per row, 256 thr x float4.
__global__ __launch_bounds__(256) void ln_k(const float* __restrict__ xin,
                                            const float* __restrict__ res,
                                            const float* __restrict__ g,
                                            const float* __restrict__ b,
                                            float* __restrict__ out) {
    const int row = blockIdx.x, tid = threadIdx.x;
    float4 v = ((const float4*)(xin + (size_t)row * H_))[tid];
    float4 rv = ((const float4*)(res + (size_t)row * H_))[tid];
    v.x += rv.x; v.y += rv.y; v.z += rv.z; v.w += rv.w;
    float s = v.x + v.y + v.z + v.w;
    float ss = v.x * v.x + v.y * v.y + v.z * v.z + v.w * v.w;
#pragma unroll
    for (int o = 1; o < 64; o <<= 1) {
        s += __shfl_xor(s, o);
        ss += __shfl_xor(ss, o);
    }
    __shared__ float sm[8];
    const int w = tid >> 6, ln = tid & 63;
    if (ln == 0) { sm[w] = s; sm[4 + w] = ss; }
    __syncthreads();
    s = sm[0] + sm[1] + sm[2] + sm[3];
    ss = sm[4] + sm[5] + sm[6] + sm[7];
    const float mean = s * (1.f / H_);
    const float var = ss * (1.f / H_) - mean * mean;
    const float rstd = rsqrtf(var + 1e-5f);
    const float4 g4 = ((const float4*)g)[tid];
    const float4 b4 = ((const float4*)b)[tid];
    float4 o;
    o.x = (v.x - mean) * rstd * g4.x + b4.x;
    o.y = (v.y - mean) * rstd * g4.y + b4.y;
    o.z = (v.z - mean) * rstd * g4.z + b4.z;
    o.w = (v.w - mean) * rstd * g4.w + b4.w;
    ((float4*)(out + (size_t)row * H_))[tid] = o;
}

// ---------------------------------------------------------------- MoE gating
__global__ __launch_bounds__(64) void gate_k(const float* __restrict__ x,
                                             const float* __restrict__ gw,
                                             const float* __restrict__ gb,
                                             int* __restrict__ topi,
                                             int* __restrict__ cnt) {
    const int t = blockIdx.x, lane = threadIdx.x;
    float acc[8] = {0, 0, 0, 0, 0, 0, 0, 0};
    const float* xr = x + (size_t)t * H_;
    for (int h = lane; h < H_; h += 64) {
        const float xv = xr[h];
        const float4 wa = ((const float4*)(gw + h * 8))[0];
        const float4 wb = ((const float4*)(gw + h * 8))[1];
        acc[0] += xv * wa.x; acc[1] += xv * wa.y;
        acc[2] += xv * wa.z; acc[3] += xv * wa.w;
        acc[4] += xv * wb.x; acc[5] += xv * wb.y;
        acc[6] += xv * wb.z; acc[7] += xv * wb.w;
    }
#pragma unroll
    for (int o = 1; o < 64; o <<= 1)
#pragma unroll
        for (int e = 0; e < 8; e++) acc[e] += __shfl_xor(acc[e], o);
    if (lane == 0) {
#pragma unroll
        for (int e = 0; e < 8; e++) acc[e] += gb[e];
        int e1 = 0; float v1 = acc[0];
#pragma unroll
        for (int e = 1; e < 8; e++)
            if (acc[e] > v1) { v1 = acc[e]; e1 = e; }
        int e2 = -1; float v2 = -1e30f;
#pragma unroll
        for (int e = 0; e < 8; e++)
            if (e != e1 && acc[e] > v2) { v2 = acc[e]; e2 = e; }
        topi[2 * t] = e1;
        topi[2 * t + 1] = e2;
        atomicAdd(&cnt[e1], 1);
        atomicAdd(&cnt[e2], 1);
    }
}

__global__ void scan_k(const int* __restrict__ cnt, int* __restrict__ off) {
    if (threadIdx.x == 0 && blockIdx.x == 0) {
        int a = 0;
        for (int e = 0; e < 8; e++) { off[e] = a; a += cnt[e]; }
        off[8] = a;
    }
}

__global__ __launch_bounds__(256) void scatter_k(const int* __restrict__ topi,
                                                 const int* __restrict__ off,
                                                 int* __restrict__ cur,
                                                 int* __restrict__ list) {
    const int t = blockIdx.x * 256 + threadIdx.x;
    if (t >= T_) return;
    const int e1 = topi[2 * t], e2 = topi[2 * t + 1];
    int p = atomicAdd(&cur[e1], 1);
    list[off[e1] + p] = 2 * t;
    p = atomicAdd(&cur[e2], 1);
    list[off[e2] + p] = 2 * t + 1;
}

// x[t] = y[2t] + y[2t+1]   (MoE replaces x, no residual)
__global__ __launch_bounds__(256) void combine_k(const float* __restrict__ y,
                                                 float* __restrict__ x) {
    const int t = blockIdx.x, tid = threadIdx.x;
    const float4 a = ((const float4*)(y + (size_t)(2 * t) * H_))[tid];
    const float4 b = ((const float4*)(y + (size_t)(2 * t + 1) * H_))[tid];
    float4 o = {a.x + b.x, a.y + b.y, a.z + b.z, a.w + b.w};
    ((float4*)(x + (size_t)t * H_))[tid] = o;
}

// ---------------------------------------------------------------- launch
extern "C" void kernel_launch(void* const* d_in, const int* in_sizes, int n_in,
                              void* d_out, int out_size, void* d_ws, size_t ws_size,
                              hipStream_t stream) {
    (void)in_sizes; (void)n_in; (void)out_size; (void)ws_size;
    const int*   ids  = (const int*)d_in[0];
    const float* emb  = (const float*)d_in[1];
    const float* qkvw = (const float*)d_in[2];
    const float* qkvb = (const float*)d_in[3];
    const float* outw = (const float*)d_in[4];
    const float* outb = (const float*)d_in[5];
    const float* ln1g = (const float*)d_in[6];
    const float* ln1b = (const float*)d_in[7];
    const float* ffw1 = (const float*)d_in[8];
    const float* ffb1 = (const float*)d_in[9];
    const float* ffw2 = (const float*)d_in[10];
    const float* ffb2 = (const float*)d_in[11];
    const float* ln2g = (const float*)d_in[12];
    const float* ln2b = (const float*)d_in[13];
    const float* gw   = (const float*)d_in[14];
    const float* gb   = (const float*)d_in[15];
    const float* ew1  = (const float*)d_in[16];
    const float* eb1  = (const float*)d_in[17];
    const float* ew2  = (const float*)d_in[18];
    const float* eb2  = (const float*)d_in[19];
    const float* lmw  = (const float*)d_in[20];
    const float* lmb  = (const float*)d_in[21];
    float* out = (float*)d_out;

    // workspace layout (floats): x | bufA (qkv / ff-hidden / expert-hidden) | bufB (ao / expert-y) | ints
    float* x    = (float*)d_ws;
    float* bufA = x + (size_t)T_ * H_;              // 16.78M floats
    float* bufB = bufA + (size_t)T_ * 4 * H_;       // 8.39M floats
    int* ib  = (int*)(bufB + (size_t)2 * T_ * H_);
    int* cnt = ib;          // [8]
    int* cur = ib + 8;      // [8]
    int* off = ib + 16;     // [9]
    int* topi = ib + 32;    // [2T]
    int* list = ib + 32 + 2 * T_;  // [2T]

    embed_k<<<T_, 256, 0, stream>>>(ids, emb, x);

    for (int l = 0; l < L_; l++) {
        // QKV projection: x @ W^T
        gemm_k<true, 0><<<dim3(3 * H_ / 64, T_ / 64), 256, 0, stream>>>(
            x, qkvw + (size_t)l * 3 * H_ * H_, qkvb + l * 3 * H_, bufA, 3 * H_, H_);
        // flash attention -> bufB
        attn_k<<<dim3(S_ / 32, B_ * NH_), 256, 0, stream>>>(bufA, bufB);
        // out projection -> bufA
        gemm_k<true, 0><<<dim3(H_ / 64, T_ / 64), 256, 0, stream>>>(
            bufB, outw + (size_t)l * H_ * H_, outb + l * H_, bufA, H_, H_);
        // x = LN(x + attn_out)
        ln_k<<<T_, 256, 0, stream>>>(bufA, x, ln1g + l * H_, ln1b + l * H_, x);
        // FFN
        gemm_k<false, 1><<<dim3(FF_ / 64, T_ / 64), 256, 0, stream>>>(
            x, ffw1 + (size_t)l * H_ * FF_, ffb1 + l * FF_, bufA, FF_, H_);
        gemm_k<false, 0><<<dim3(H_ / 64, T_ / 64), 256, 0, stream>>>(
            bufA, ffw2 + (size_t)l * FF_ * H_, ffb2 + l * H_, bufB, H_, FF_);
        // x = LN(x + ff)
        ln_k<<<T_, 256, 0, stream>>>(bufB, x, ln2g + l * H_, ln2b + l * H_, x);
        // MoE: gate -> bucket by expert -> gathered GEMMs -> combine
        hipMemsetAsync(cnt, 0, 16 * sizeof(int), stream);  // cnt + cur
        gate_k<<<T_, 64, 0, stream>>>(x, gw + (size_t)l * H_ * E_, gb + l * E_, topi, cnt);
        scan_k<<<1, 64, 0, stream>>>(cnt, off);
        scatter_k<<<T_ / 256, 256, 0, stream>>>(topi, off, cur, list);
        gemm_exp<2, true, false><<<dim3(2 * H_ / 64, 512), 256, 0, stream>>>(
            x, ew1 + (size_t)l * E_ * H_ * 2 * H_, eb1 + (size_t)l * E_ * 2 * H_,
            bufA, list, off, cnt, 2 * H_, H_);
        gemm_exp<0, false, true><<<dim3(H_ / 64, 512), 256, 0, stream>>>(
            bufA, ew2 + (size_t)l * E_ * 2 * H_ * H_, eb2 + (size_t)l * E_ * H_,
            bufB, list, off, cnt, H_, 2 * H_);
        combine_k<<<T_, 256, 0, stream>>>(bufB, x);
    }

    // LM head: [4096,1024] @ [1024,32000]
    gemm_k<false, 0><<<dim3(V_ / 64, T_ / 64), 256, 0, stream>>>(
        x, lmw, lmb, out, V_, H_);
}